// Round 3
// baseline (43460.654 us; speedup 1.0000x reference)
//
#include <hip/hip_runtime.h>

#define KK 67
#define DIN 4
#define CLIPM 16
#define NEPOCH 5

typedef float float2v __attribute__((ext_vector_type(2)));

__device__ __forceinline__ float ex2(float x) {
#if __has_builtin(__builtin_amdgcn_exp2f)
    return __builtin_amdgcn_exp2f(x);
#else
    return exp2f(x);
#endif
}
__device__ __forceinline__ float frcp(float x) {
#if __has_builtin(__builtin_amdgcn_rcpf)
    return __builtin_amdgcn_rcpf(x);
#else
    return 1.0f / x;
#endif
}

// VOP3P packed FMA. All sources are VGPR pairs. Broadcast one half of the
// x-pair to both result lanes via op_sel / op_sel_hi:
//   lo: both lanes read src0.lo   hi: both lanes read src0.hi
__device__ __forceinline__ void pkfma_lo(float2v& acc, float2v x, float2v w) {
    asm("v_pk_fma_f32 %0, %1, %2, %0 op_sel:[0,0,0] op_sel_hi:[0,1,1]"
        : "+v"(acc) : "v"(x), "v"(w));
}
__device__ __forceinline__ void pkfma_hi(float2v& acc, float2v x, float2v w) {
    asm("v_pk_fma_f32 %0, %1, %2, %0 op_sel:[1,0,0] op_sel_hi:[1,1,1]"
        : "+v"(acc) : "v"(x), "v"(w));
}

// own-group broadcast of element j: new_lane = (lane & 0b11000) | j (lane[5] kept)
#define SWZ(v, j) __int_as_float(__builtin_amdgcn_ds_swizzle(__float_as_int(v), (((j) << 5) | 24)))
__device__ __forceinline__ float bperm(int byteaddr, float v) {
    return __int_as_float(__builtin_amdgcn_ds_bpermute(byteaddr, __float_as_int(v)));
}

// ---------------- Phase 1: per-frame GRNN + projections (parallel over T) ----------------
__global__ __launch_bounds__(128) void grnn_kernel(
    const float* __restrict__ vid,
    const float* __restrict__ W1, const float* __restrict__ b1,
    const float* __restrict__ gw, const float* __restrict__ gb,
    const float* __restrict__ gWih, const float* __restrict__ gWhh,
    const float* __restrict__ gbih, const float* __restrict__ gbhh,
    const float* __restrict__ W2, const float* __restrict__ b2,
    float* __restrict__ q)
{
    const int f = blockIdx.x;
    const int t = threadIdx.x;
    const int k = t;
    __shared__ float sWih[256], sWhh[256], sb[32], sW1[32], sb1[8], sW2[64], sb2[8];
    __shared__ float Msum[8];
    for (int i = t; i < 256; i += 128) { sWih[i] = gWih[i]; sWhh[i] = gWhh[i]; }
    if (t < 32) sb[t] = gbih[t] + gbhh[t];
    if (t < 32) sW1[t] = W1[t];
    if (t < 8)  sb1[t] = b1[t];
    if (t < 64) sW2[t] = W2[t];
    if (t < 8)  sb2[t] = b2[t];
    __syncthreads();

    const bool act = (k < KK);
    float R[8], S[8], gwl[8], gbl[8];
    if (act) {
        const float* vp = vid + ((size_t)f * KK + k) * DIN;
        const float v0 = vp[0], v1 = vp[1], v2 = vp[2], v3 = vp[3];
#pragma unroll
        for (int j = 0; j < 8; ++j) {
            R[j] = sb1[j] + sW1[j*4+0]*v0 + sW1[j*4+1]*v1 + sW1[j*4+2]*v2 + sW1[j*4+3]*v3;
            S[j] = 0.0f;
            gwl[j] = gw[k*8 + j];
            gbl[j] = gb[k*8 + j];
        }
    }
    for (int e = 0; e < NEPOCH; ++e) {
        if (t < 8) Msum[t] = 0.0f;
        __syncthreads();
        float per[8];
        if (act) {
#pragma unroll
            for (int j = 0; j < 8; ++j) { per[j] = gwl[j]*S[j] + gbl[j]; atomicAdd(&Msum[j], per[j]); }
        }
        __syncthreads();
        if (act) {
            float M[8];
#pragma unroll
            for (int j = 0; j < 8; ++j) M[j] = Msum[j] - per[j];
            float gv[32];
#pragma unroll
            for (int gg = 0; gg < 32; ++gg) {
                float a = sb[gg];
#pragma unroll
                for (int j = 0; j < 8; ++j)
                    a = fmaf(R[j], sWih[gg*8+j], fmaf(M[j], sWhh[gg*8+j], a));
                gv[gg] = a;
            }
#pragma unroll
            for (int j = 0; j < 8; ++j) {
                float sg_i = frcp(1.f + ex2(-1.4426950408889634f * gv[j]));
                float sg_f = frcp(1.f + ex2(-1.4426950408889634f * gv[8+j]));
                float th_g = 1.f - 2.f * frcp(1.f + ex2(2.8853900817779268f * gv[16+j]));
                float sg_o = frcp(1.f + ex2(-1.4426950408889634f * gv[24+j]));
                float c2 = sg_f * S[j] + sg_i * th_g;
                float h2 = sg_o * (1.f - 2.f * frcp(1.f + ex2(2.8853900817779268f * c2)));
                R[j] += S[j];   // updateRelation uses OLD lastS
                S[j] = h2;
            }
        }
        __syncthreads();
    }
    if (act) {
        float* qp = q + ((size_t)f * KK + k) * 8;
#pragma unroll
        for (int jo = 0; jo < 8; ++jo) {
            float a = sb2[jo];
#pragma unroll
            for (int j = 0; j < 8; ++j) a = fmaf(fmaxf(R[j], 0.0f), sW2[jo*8+j], a);
            qp[jo] = a;
        }
    }
}

// ---------------- Phase 2: two skip-LSTM chains, register-only wavefront ----------------
// Block 0 = P chain (input q[u]), block 1 = V chain (input q[u]-q[u-67]).
// One wave per block; lane = l*8+s owns gate rows {i,f,g,o} x s of layer l.
// Exchange between steps is pure crossbar: ds_swizzle (own-layer h), ds_bpermute
// (layer-below y; group 0 pulls the q-injection from group 7's source register).
__global__ __launch_bounds__(64, 1) void slstm_kernel(
    const float* __restrict__ q,
    const float* __restrict__ pWih, const float* __restrict__ pWhh,
    const float* __restrict__ pbih, const float* __restrict__ pbhh,
    const float* __restrict__ vWih, const float* __restrict__ vWhh,
    const float* __restrict__ vbih, const float* __restrict__ vbhh,
    float* __restrict__ out, int U, int N)
{
    const int lane = threadIdx.x;
    const int l = lane >> 3, s = lane & 7;
    const int isV = blockIdx.x;
    const float* Wih = isV ? vWih : pWih;
    const float* Whh = isV ? vWhh : pWhh;
    const float* bi  = isV ? vbih : pbih;
    const float* bh  = isV ? vbhh : pbhh;
    float* ob = out + (size_t)isV * (size_t)N * 64;

    const float cS = -1.4426950408889634f;   // -log2(e): i,f,o rows (sigmoid)
    const float cT =  2.8853900817779268f;   // 2*log2(e): g row (tanh)

    // weights pre-scaled so activations need no input mul:
    //   sig(x) = rcp(1 + exp2(a)),  a = cS*x ; tanh(x) = 1 - 2*rcp(1 + exp2(a)), a = cT*x
    float2v wih01[8], wih23[8], whh01[8], whh23[8], b01, b23;
    {
        const int r_i = l*32 + 0*8 + s, r_f = l*32 + 1*8 + s;
        const int r_g = l*32 + 2*8 + s, r_o = l*32 + 3*8 + s;
#pragma unroll
        for (int j = 0; j < 8; ++j) {
            wih01[j] = float2v{cS * Wih[r_i*8+j], cS * Wih[r_f*8+j]};
            wih23[j] = float2v{cT * Wih[r_g*8+j], cS * Wih[r_o*8+j]};
            whh01[j] = float2v{cS * Whh[r_i*8+j], cS * Whh[r_f*8+j]};
            whh23[j] = float2v{cT * Whh[r_g*8+j], cS * Whh[r_o*8+j]};
        }
        b01 = float2v{cS*(bi[r_i]+bh[r_i]), cS*(bi[r_f]+bh[r_f])};
        b23 = float2v{cT*(bi[r_g]+bh[r_g]), cS*(bi[r_o]+bh[r_o])};
    }

    // bpermute byte addresses: x[j] from group (l-1)&7 (group 0 sources group 7 = q inject)
    int ay[8];
#pragma unroll
    for (int j = 0; j < 8; ++j) ay[j] = ((((l + 7) & 7) * 8 + j) << 2);
    const int axo = ((lane + 56) & 63) << 2;   // own-column x (for skip connection)

    float hp = 0.f, c = 0.f, Hm = 0.f, Hc = 0.f;
    const bool g7 = (l == 7);
    const float vsel = isV ? 1.0f : 0.0f;

    float ysrcv = g7 ? q[s] : 0.f;   // seed: group 7 sources q(u=0)

    auto core = [&](float& h2o, float& c2o, float& xoo) {
        float2v xp[4], hq[4];
        xp[0].x = bperm(ay[0], ysrcv); xp[0].y = bperm(ay[1], ysrcv);
        xp[1].x = bperm(ay[2], ysrcv); xp[1].y = bperm(ay[3], ysrcv);
        xp[2].x = bperm(ay[4], ysrcv); xp[2].y = bperm(ay[5], ysrcv);
        xp[3].x = bperm(ay[6], ysrcv); xp[3].y = bperm(ay[7], ysrcv);
        const float xo = bperm(axo, ysrcv);
        hq[0].x = SWZ(hp, 0); hq[0].y = SWZ(hp, 1);
        hq[1].x = SWZ(hp, 2); hq[1].y = SWZ(hp, 3);
        hq[2].x = SWZ(hp, 4); hq[2].y = SWZ(hp, 5);
        hq[3].x = SWZ(hp, 6); hq[3].y = SWZ(hp, 7);
        float2v a01 = b01, a23 = b23;
        float2v g01 = {0.f, 0.f}, g23 = {0.f, 0.f};
#pragma unroll
        for (int j = 0; j < 4; ++j) {
            pkfma_lo(a01, xp[j], wih01[2*j]);
            pkfma_hi(a01, xp[j], wih01[2*j+1]);
            pkfma_lo(a23, xp[j], wih23[2*j]);
            pkfma_hi(a23, xp[j], wih23[2*j+1]);
            pkfma_lo(g01, hq[j], whh01[2*j]);
            pkfma_hi(g01, hq[j], whh01[2*j+1]);
            pkfma_lo(g23, hq[j], whh23[2*j]);
            pkfma_hi(g23, hq[j], whh23[2*j+1]);
        }
        a01 = a01 + g01;
        a23 = a23 + g23;
        const float ig = frcp(1.f + ex2(a01.x));
        const float fg = frcp(1.f + ex2(a01.y));
        const float gt = fmaf(-2.f, frcp(1.f + ex2(a23.x)), 1.f);
        const float og = frcp(1.f + ex2(a23.y));
        const float c2 = fmaf(fg, c, ig * gt);
        const float th = fmaf(-2.f, frcp(1.f + ex2(c2 * cT)), 1.f);
        h2o = og * th;
        c2o = c2;
        xoo = xo;
    };

    // ---- startup: d = 0..6 (direct loads, act = l <= d) ----
    for (int d = 0; d < 7; ++d) {
        float h2, c2n, xo;
        core(h2, c2n, xo);
        const bool act = (l <= d);
        hp = act ? h2 : 0.f;
        c  = act ? c2n : c;
        const float y = h2 + xo;
        const float qa = q[(d+1)*8 + s];   // u = d+1 <= 7 < 67: no V subtract
        ysrcv = g7 ? qa : y;
    }

    // ---- prefetch rings (static slot p consumes u = d0+1+p) ----
    float ra[4], rb[4];
#pragma unroll
    for (int p = 0; p < 4; ++p) { ra[p] = q[(8+p)*8 + s]; rb[p] = 0.f; }

    int d0 = 7;
    const int maxu = U - 1;
    for (int k = 0; k < N; ++k) {
        // 1064 clean steps: no boundary / activity logic at all
        for (int it = 0; it < 266; ++it) {
#pragma unroll
            for (int p = 0; p < 4; ++p) {
                const int u = d0 + 1 + p;
                float h2, c2n, xo;
                core(h2, c2n, xo);
                c = c2n;
                hp = h2;
                const float y = h2 + xo;
                const float qb = (u >= KK) ? rb[p] : 0.f;
                const float qc = fmaf(-vsel, qb, ra[p]);
                ysrcv = g7 ? qc : y;
                int ua = u + 4; if (ua > maxu) ua = maxu;
                ra[p] = q[ua*8 + s];
                int ub = ua - KK; if (ub < 0) ub = 0;
                rb[p] = q[ub*8 + s];
            }
            d0 += 4;
        }
        // boundary cluster: 8 steps, delta = 0..7; lane group l resets at delta == l
        const bool lastk = (k == N - 1);
        for (int j2 = 0; j2 < 2; ++j2) {
#pragma unroll
            for (int p = 0; p < 4; ++p) {
                const int dlt = j2*4 + p;
                const int u = d0 + 1 + p;
                float h2, c2n, xo;
                core(h2, c2n, xo);
                const bool bnd = (l == dlt);
                const bool act = (!lastk) || (dlt <= l);
                const float HmN = Hm + h2, HcN = Hc + c2n;
                const float hpN = bnd ? HmN : h2;
                const float cN  = bnd ? HcN : c2n;
                hp = act ? hpN : hp;
                c  = act ? cN  : c;
                Hm = bnd ? HmN : Hm;
                Hc = bnd ? HcN : Hc;
                if (bnd) ob[(size_t)k * 64 + lane] = HmN;
                const float y = h2 + xo;
                const float qb = (u >= KK) ? rb[p] : 0.f;
                const float qc = fmaf(-vsel, qb, ra[p]);
                ysrcv = g7 ? qc : y;
                int ua = u + 4; if (ua > maxu) ua = maxu;
                ra[p] = q[ua*8 + s];
                int ub = ua - KK; if (ub < 0) ub = 0;
                rb[p] = q[ub*8 + s];
            }
            d0 += 4;
        }
    }
}

extern "C" void kernel_launch(void* const* d_in, const int* in_sizes, int n_in,
                              void* d_out, int out_size, void* d_ws, size_t ws_size,
                              hipStream_t stream)
{
    const float* vid  = (const float*)d_in[0];
    const float* W1   = (const float*)d_in[1];
    const float* b1   = (const float*)d_in[2];
    const float* gw   = (const float*)d_in[3];
    const float* gb   = (const float*)d_in[4];
    const float* gWih = (const float*)d_in[5];
    const float* gWhh = (const float*)d_in[6];
    const float* gbih = (const float*)d_in[7];
    const float* gbhh = (const float*)d_in[8];
    const float* W2   = (const float*)d_in[9];
    const float* b2   = (const float*)d_in[10];
    const float* vWih = (const float*)d_in[11];
    const float* vWhh = (const float*)d_in[12];
    const float* vbih = (const float*)d_in[13];
    const float* vbhh = (const float*)d_in[14];
    const float* pWih = (const float*)d_in[15];
    const float* pWhh = (const float*)d_in[16];
    const float* pbih = (const float*)d_in[17];
    const float* pbhh = (const float*)d_in[18];

    const int T = in_sizes[0] / (KK * DIN);
    const int N = T / CLIPM;
    const int U = N * CLIPM * KK;
    float* q = (float*)d_ws;   // T*KK*8 floats = 4.4 MB

    grnn_kernel<<<dim3(T), dim3(128), 0, stream>>>(
        vid, W1, b1, gw, gb, gWih, gWhh, gbih, gbhh, W2, b2, q);
    slstm_kernel<<<dim3(2), dim3(64), 0, stream>>>(
        q, pWih, pWhh, pbih, pbhh, vWih, vWhh, vbih, vbhh, (float*)d_out, U, N);
}

// Round 4
// 28800.873 us; speedup vs baseline: 1.5090x; 1.5090x over previous
//
#include <hip/hip_runtime.h>

#define KK 67
#define DIN 4
#define CLIPM 16
#define NEPOCH 5

typedef float float2v __attribute__((ext_vector_type(2)));

__device__ __forceinline__ float ex2(float x) {
#if __has_builtin(__builtin_amdgcn_exp2f)
    return __builtin_amdgcn_exp2f(x);
#else
    return exp2f(x);
#endif
}
__device__ __forceinline__ float frcp(float x) {
#if __has_builtin(__builtin_amdgcn_rcpf)
    return __builtin_amdgcn_rcpf(x);
#else
    return 1.0f / x;
#endif
}

// VOP3P packed FMA. All sources are VGPR pairs. Broadcast one half of the
// x-pair to both result lanes via op_sel / op_sel_hi.
__device__ __forceinline__ void pkfma_lo(float2v& acc, float2v x, float2v w) {
    asm("v_pk_fma_f32 %0, %1, %2, %0 op_sel:[0,0,0] op_sel_hi:[0,1,1]"
        : "+v"(acc) : "v"(x), "v"(w));
}
__device__ __forceinline__ void pkfma_hi(float2v& acc, float2v x, float2v w) {
    asm("v_pk_fma_f32 %0, %1, %2, %0 op_sel:[1,0,0] op_sel_hi:[1,1,1]"
        : "+v"(acc) : "v"(x), "v"(w));
}

// DPP lane shuffles (VALU pipe, ~2cy). 0xB1=quad xor1, 0x4E=quad xor2,
// 0x141=row_half_mirror (xor7 within 8-lane half-row).
template<int CTRL>
__device__ __forceinline__ float dppf(float v) {
    return __int_as_float(__builtin_amdgcn_mov_dpp(__float_as_int(v), CTRL, 0xF, 0xF, false));
}
__device__ __forceinline__ float bperm(int byteaddr, float v) {
    return __int_as_float(__builtin_amdgcn_ds_bpermute(byteaddr, __float_as_int(v)));
}

// ---------------- Phase 1: per-frame GRNN + projections (parallel over T) ----------------
__global__ __launch_bounds__(128) void grnn_kernel(
    const float* __restrict__ vid,
    const float* __restrict__ W1, const float* __restrict__ b1,
    const float* __restrict__ gw, const float* __restrict__ gb,
    const float* __restrict__ gWih, const float* __restrict__ gWhh,
    const float* __restrict__ gbih, const float* __restrict__ gbhh,
    const float* __restrict__ W2, const float* __restrict__ b2,
    float* __restrict__ q)
{
    const int f = blockIdx.x;
    const int t = threadIdx.x;
    const int k = t;
    __shared__ float sWih[256], sWhh[256], sb[32], sW1[32], sb1[8], sW2[64], sb2[8];
    __shared__ float Msum[8];
    for (int i = t; i < 256; i += 128) { sWih[i] = gWih[i]; sWhh[i] = gWhh[i]; }
    if (t < 32) sb[t] = gbih[t] + gbhh[t];
    if (t < 32) sW1[t] = W1[t];
    if (t < 8)  sb1[t] = b1[t];
    if (t < 64) sW2[t] = W2[t];
    if (t < 8)  sb2[t] = b2[t];
    __syncthreads();

    const bool act = (k < KK);
    float R[8], S[8], gwl[8], gbl[8];
    if (act) {
        const float* vp = vid + ((size_t)f * KK + k) * DIN;
        const float v0 = vp[0], v1 = vp[1], v2 = vp[2], v3 = vp[3];
#pragma unroll
        for (int j = 0; j < 8; ++j) {
            R[j] = sb1[j] + sW1[j*4+0]*v0 + sW1[j*4+1]*v1 + sW1[j*4+2]*v2 + sW1[j*4+3]*v3;
            S[j] = 0.0f;
            gwl[j] = gw[k*8 + j];
            gbl[j] = gb[k*8 + j];
        }
    }
    for (int e = 0; e < NEPOCH; ++e) {
        if (t < 8) Msum[t] = 0.0f;
        __syncthreads();
        float per[8];
        if (act) {
#pragma unroll
            for (int j = 0; j < 8; ++j) { per[j] = gwl[j]*S[j] + gbl[j]; atomicAdd(&Msum[j], per[j]); }
        }
        __syncthreads();
        if (act) {
            float M[8];
#pragma unroll
            for (int j = 0; j < 8; ++j) M[j] = Msum[j] - per[j];
            float gv[32];
#pragma unroll
            for (int gg = 0; gg < 32; ++gg) {
                float a = sb[gg];
#pragma unroll
                for (int j = 0; j < 8; ++j)
                    a = fmaf(R[j], sWih[gg*8+j], fmaf(M[j], sWhh[gg*8+j], a));
                gv[gg] = a;
            }
#pragma unroll
            for (int j = 0; j < 8; ++j) {
                float sg_i = frcp(1.f + ex2(-1.4426950408889634f * gv[j]));
                float sg_f = frcp(1.f + ex2(-1.4426950408889634f * gv[8+j]));
                float th_g = 1.f - 2.f * frcp(1.f + ex2(2.8853900817779268f * gv[16+j]));
                float sg_o = frcp(1.f + ex2(-1.4426950408889634f * gv[24+j]));
                float c2 = sg_f * S[j] + sg_i * th_g;
                float h2 = sg_o * (1.f - 2.f * frcp(1.f + ex2(2.8853900817779268f * c2)));
                R[j] += S[j];   // updateRelation uses OLD lastS
                S[j] = h2;
            }
        }
        __syncthreads();
    }
    if (act) {
        float* qp = q + ((size_t)f * KK + k) * 8;
#pragma unroll
        for (int jo = 0; jo < 8; ++jo) {
            float a = sb2[jo];
#pragma unroll
            for (int j = 0; j < 8; ++j) a = fmaf(fmaxf(R[j], 0.0f), sW2[jo*8+j], a);
            qp[jo] = a;
        }
    }
}

// ---------------- Phase 2: two skip-LSTM chains, DPP-exchange wavefront ----------------
// Block 0 = P chain (input q[u]), block 1 = V chain (input q[u]-q[u-67]).
// One wave per block; lane = l*8+s owns gate rows {i,f,g,o} x s of layer l.
// Exchange: 1 ds_bpermute (shift layer-below y by 8 lanes) + 14 DPP movs
// (butterfly all-gather within 8-lane groups; slot k holds element s^M[k],
// compensated by permuting weight load order).
__global__ __launch_bounds__(64, 1) void slstm_kernel(
    const float* __restrict__ q,
    const float* __restrict__ pWih, const float* __restrict__ pWhh,
    const float* __restrict__ pbih, const float* __restrict__ pbhh,
    const float* __restrict__ vWih, const float* __restrict__ vWhh,
    const float* __restrict__ vbih, const float* __restrict__ vbhh,
    float* __restrict__ out, int U, int N)
{
    const int lane = threadIdx.x;
    const int l = lane >> 3, s = lane & 7;
    const int isV = blockIdx.x;
    const float* Wih = isV ? vWih : pWih;
    const float* Whh = isV ? vWhh : pWhh;
    const float* bi  = isV ? vbih : pbih;
    const float* bh  = isV ? vbhh : pbhh;
    float* ob = out + (size_t)isV * (size_t)N * 64;

    const float cS = -1.4426950408889634f;   // -log2(e): i,f,o rows (sigmoid)
    const float cT =  2.8853900817779268f;   // 2*log2(e): g row (tanh)

    // Gather slot k holds element j = s ^ M[k] (DPP butterfly order).
    const int M[8] = {0, 1, 2, 3, 7, 6, 5, 4};

    float2v wih01[8], wih23[8], whh01[8], whh23[8], b01, b23;
    {
        const int r_i = l*32 + 0*8 + s, r_f = l*32 + 1*8 + s;
        const int r_g = l*32 + 2*8 + s, r_o = l*32 + 3*8 + s;
#pragma unroll
        for (int k = 0; k < 8; ++k) {
            const int j = s ^ M[k];
            wih01[k] = float2v{cS * Wih[r_i*8+j], cS * Wih[r_f*8+j]};
            wih23[k] = float2v{cT * Wih[r_g*8+j], cS * Wih[r_o*8+j]};
            whh01[k] = float2v{cS * Whh[r_i*8+j], cS * Whh[r_f*8+j]};
            whh23[k] = float2v{cT * Whh[r_g*8+j], cS * Whh[r_o*8+j]};
        }
        b01 = float2v{cS*(bi[r_i]+bh[r_i]), cS*(bi[r_f]+bh[r_f])};
        b23 = float2v{cT*(bi[r_g]+bh[r_g]), cS*(bi[r_o]+bh[r_o])};
    }

    const int axo = ((lane + 56) & 63) << 2;   // pull y from lane-8 (group l-1)

    float hp = 0.f, c = 0.f, Hm = 0.f, Hc = 0.f;
    const bool g7 = (l == 7);
    const float vsel = isV ? 1.0f : 0.0f;

    float ysrcv = g7 ? q[s] : 0.f;   // seed: group 7 sources q(u=0)

    auto core = [&](float& h2o, float& c2o, float& xoo) {
        // h all-gather (pure VALU, ready early -> overlaps the bpermute)
        const float hA = dppf<0xB1>(hp);
        const float hB = dppf<0x4E>(hp);
        const float hC = dppf<0x4E>(hA);
        const float hD = dppf<0x141>(hp);
        const float hE = dppf<0x141>(hA);
        const float hF = dppf<0x141>(hB);
        const float hG = dppf<0x141>(hC);
        const float2v hq0 = {hp, hA}, hq1 = {hB, hC}, hq2 = {hD, hE}, hq3 = {hF, hG};
        float2v g01 = {0.f, 0.f}, g23 = {0.f, 0.f};
        pkfma_lo(g01, hq0, whh01[0]); pkfma_hi(g01, hq0, whh01[1]);
        pkfma_lo(g23, hq0, whh23[0]); pkfma_hi(g23, hq0, whh23[1]);
        pkfma_lo(g01, hq1, whh01[2]); pkfma_hi(g01, hq1, whh01[3]);
        pkfma_lo(g23, hq1, whh23[2]); pkfma_hi(g23, hq1, whh23[3]);
        pkfma_lo(g01, hq2, whh01[4]); pkfma_hi(g01, hq2, whh01[5]);
        pkfma_lo(g23, hq2, whh23[4]); pkfma_hi(g23, hq2, whh23[5]);
        pkfma_lo(g01, hq3, whh01[6]); pkfma_hi(g01, hq3, whh01[7]);
        pkfma_lo(g23, hq3, whh23[6]); pkfma_hi(g23, hq3, whh23[7]);
        // x: one crossbar shift, then DPP all-gather
        const float ytmp = bperm(axo, ysrcv);
        const float xA = dppf<0xB1>(ytmp);
        const float xB = dppf<0x4E>(ytmp);
        const float xC = dppf<0x4E>(xA);
        const float xD = dppf<0x141>(ytmp);
        const float xE = dppf<0x141>(xA);
        const float xF = dppf<0x141>(xB);
        const float xG = dppf<0x141>(xC);
        const float2v xp0 = {ytmp, xA}, xp1 = {xB, xC}, xp2 = {xD, xE}, xp3 = {xF, xG};
        float2v a01 = b01, a23 = b23;
        pkfma_lo(a01, xp0, wih01[0]); pkfma_hi(a01, xp0, wih01[1]);
        pkfma_lo(a23, xp0, wih23[0]); pkfma_hi(a23, xp0, wih23[1]);
        pkfma_lo(a01, xp1, wih01[2]); pkfma_hi(a01, xp1, wih01[3]);
        pkfma_lo(a23, xp1, wih23[2]); pkfma_hi(a23, xp1, wih23[3]);
        pkfma_lo(a01, xp2, wih01[4]); pkfma_hi(a01, xp2, wih01[5]);
        pkfma_lo(a23, xp2, wih23[4]); pkfma_hi(a23, xp2, wih23[5]);
        pkfma_lo(a01, xp3, wih01[6]); pkfma_hi(a01, xp3, wih01[7]);
        pkfma_lo(a23, xp3, wih23[6]); pkfma_hi(a23, xp3, wih23[7]);
        a01 = a01 + g01;
        a23 = a23 + g23;
        const float ig = frcp(1.f + ex2(a01.x));
        const float fg = frcp(1.f + ex2(a01.y));
        const float gt = fmaf(-2.f, frcp(1.f + ex2(a23.x)), 1.f);
        const float og = frcp(1.f + ex2(a23.y));
        const float c2 = fmaf(fg, c, ig * gt);
        const float th = fmaf(-2.f, frcp(1.f + ex2(c2 * cT)), 1.f);
        h2o = og * th;
        c2o = c2;
        xoo = ytmp;
    };

    // ---- startup: d = 0..6 (direct loads, act = l <= d) ----
    for (int d = 0; d < 7; ++d) {
        float h2, c2n, xo;
        core(h2, c2n, xo);
        const bool act = (l <= d);
        hp = act ? h2 : 0.f;
        c  = act ? c2n : c;
        const float y = h2 + xo;
        const float qa = q[(d+1)*8 + s];   // u = d+1 <= 7 < 67: no V subtract
        ysrcv = g7 ? qa : y;
    }

    // ---- 8-deep prefetch ring (slot p consumes u = d0+1+p, refills u+8) ----
    float ra[8], rb[8];
#pragma unroll
    for (int p = 0; p < 8; ++p) { ra[p] = q[(8+p)*8 + s]; rb[p] = 0.f; }

    int d0 = 7;
    const int maxu = U - 1;
    for (int k = 0; k < N; ++k) {
        // 1064 clean steps: no boundary / activity logic at all
        for (int it = 0; it < 133; ++it) {
#pragma unroll
            for (int p = 0; p < 8; ++p) {
                const int u = d0 + 1 + p;
                float h2, c2n, xo;
                core(h2, c2n, xo);
                c = c2n;
                hp = h2;
                const float y = h2 + xo;
                const float qb = (u >= KK) ? rb[p] : 0.f;
                const float qc = fmaf(-vsel, qb, ra[p]);
                ysrcv = g7 ? qc : y;
                int ua = u + 8; if (ua > maxu) ua = maxu;
                ra[p] = q[ua*8 + s];
                int ub = ua - KK; if (ub < 0) ub = 0;
                rb[p] = q[ub*8 + s];
            }
            d0 += 8;
        }
        // boundary cluster: 8 steps, delta = 0..7; lane group l resets at delta == l
        const bool lastk = (k == N - 1);
#pragma unroll
        for (int p = 0; p < 8; ++p) {
            const int dlt = p;
            const int u = d0 + 1 + p;
            float h2, c2n, xo;
            core(h2, c2n, xo);
            const bool bnd = (l == dlt);
            const bool act = (!lastk) || (dlt <= l);
            const float HmN = Hm + h2, HcN = Hc + c2n;
            const float hpN = bnd ? HmN : h2;
            const float cN  = bnd ? HcN : c2n;
            hp = act ? hpN : hp;
            c  = act ? cN  : c;
            Hm = bnd ? HmN : Hm;
            Hc = bnd ? HcN : Hc;
            if (bnd) ob[(size_t)k * 64 + lane] = HmN;
            const float y = h2 + xo;
            const float qb = (u >= KK) ? rb[p] : 0.f;
            const float qc = fmaf(-vsel, qb, ra[p]);
            ysrcv = g7 ? qc : y;
            int ua = u + 8; if (ua > maxu) ua = maxu;
            ra[p] = q[ua*8 + s];
            int ub = ua - KK; if (ub < 0) ub = 0;
            rb[p] = q[ub*8 + s];
        }
        d0 += 8;
    }
}

extern "C" void kernel_launch(void* const* d_in, const int* in_sizes, int n_in,
                              void* d_out, int out_size, void* d_ws, size_t ws_size,
                              hipStream_t stream)
{
    const float* vid  = (const float*)d_in[0];
    const float* W1   = (const float*)d_in[1];
    const float* b1   = (const float*)d_in[2];
    const float* gw   = (const float*)d_in[3];
    const float* gb   = (const float*)d_in[4];
    const float* gWih = (const float*)d_in[5];
    const float* gWhh = (const float*)d_in[6];
    const float* gbih = (const float*)d_in[7];
    const float* gbhh = (const float*)d_in[8];
    const float* W2   = (const float*)d_in[9];
    const float* b2   = (const float*)d_in[10];
    const float* vWih = (const float*)d_in[11];
    const float* vWhh = (const float*)d_in[12];
    const float* vbih = (const float*)d_in[13];
    const float* vbhh = (const float*)d_in[14];
    const float* pWih = (const float*)d_in[15];
    const float* pWhh = (const float*)d_in[16];
    const float* pbih = (const float*)d_in[17];
    const float* pbhh = (const float*)d_in[18];

    const int T = in_sizes[0] / (KK * DIN);
    const int N = T / CLIPM;
    const int U = N * CLIPM * KK;
    float* q = (float*)d_ws;   // T*KK*8 floats = 4.4 MB

    grnn_kernel<<<dim3(T), dim3(128), 0, stream>>>(
        vid, W1, b1, gw, gb, gWih, gWhh, gbih, gbhh, W2, b2, q);
    slstm_kernel<<<dim3(2), dim3(64), 0, stream>>>(
        q, pWih, pWhh, pbih, pbhh, vWih, vWhh, vbih, vbhh, (float*)d_out, U, N);
}

// Round 5
// 27630.405 us; speedup vs baseline: 1.5729x; 1.0424x over previous
//
#include <hip/hip_runtime.h>

#define KK 67
#define DIN 4
#define CLIPM 16
#define NEPOCH 5

typedef float float2v __attribute__((ext_vector_type(2)));

__device__ __forceinline__ float ex2(float x) {
#if __has_builtin(__builtin_amdgcn_exp2f)
    return __builtin_amdgcn_exp2f(x);
#else
    return exp2f(x);
#endif
}
__device__ __forceinline__ float frcp(float x) {
#if __has_builtin(__builtin_amdgcn_rcpf)
    return __builtin_amdgcn_rcpf(x);
#else
    return 1.0f / x;
#endif
}

// VOP3P packed FMA. All sources are VGPR pairs. Broadcast one half of the
// x-pair to both result lanes via op_sel / op_sel_hi.
__device__ __forceinline__ void pkfma_lo(float2v& acc, float2v x, float2v w) {
    asm("v_pk_fma_f32 %0, %1, %2, %0 op_sel:[0,0,0] op_sel_hi:[0,1,1]"
        : "+v"(acc) : "v"(x), "v"(w));
}
__device__ __forceinline__ void pkfma_hi(float2v& acc, float2v x, float2v w) {
    asm("v_pk_fma_f32 %0, %1, %2, %0 op_sel:[1,0,0] op_sel_hi:[1,1,1]"
        : "+v"(acc) : "v"(x), "v"(w));
}

// DPP lane shuffles (VALU pipe). 0xB1=quad xor1, 0x4E=quad xor2,
// 0x141=row_half_mirror (xor7 within 8-lane half-row).
template<int CTRL>
__device__ __forceinline__ float dppf(float v) {
    return __int_as_float(__builtin_amdgcn_mov_dpp(__float_as_int(v), CTRL, 0xF, 0xF, false));
}
__device__ __forceinline__ float bperm(int byteaddr, float v) {
    return __int_as_float(__builtin_amdgcn_ds_bpermute(byteaddr, __float_as_int(v)));
}

// ---------------- Phase 1: per-frame GRNN + projections (parallel over T) ----------------
__global__ __launch_bounds__(128) void grnn_kernel(
    const float* __restrict__ vid,
    const float* __restrict__ W1, const float* __restrict__ b1,
    const float* __restrict__ gw, const float* __restrict__ gb,
    const float* __restrict__ gWih, const float* __restrict__ gWhh,
    const float* __restrict__ gbih, const float* __restrict__ gbhh,
    const float* __restrict__ W2, const float* __restrict__ b2,
    float* __restrict__ q)
{
    const int f = blockIdx.x;
    const int t = threadIdx.x;
    const int k = t;
    __shared__ float sWih[256], sWhh[256], sb[32], sW1[32], sb1[8], sW2[64], sb2[8];
    __shared__ float Msum[8];
    for (int i = t; i < 256; i += 128) { sWih[i] = gWih[i]; sWhh[i] = gWhh[i]; }
    if (t < 32) sb[t] = gbih[t] + gbhh[t];
    if (t < 32) sW1[t] = W1[t];
    if (t < 8)  sb1[t] = b1[t];
    if (t < 64) sW2[t] = W2[t];
    if (t < 8)  sb2[t] = b2[t];
    __syncthreads();

    const bool act = (k < KK);
    float R[8], S[8], gwl[8], gbl[8];
    if (act) {
        const float* vp = vid + ((size_t)f * KK + k) * DIN;
        const float v0 = vp[0], v1 = vp[1], v2 = vp[2], v3 = vp[3];
#pragma unroll
        for (int j = 0; j < 8; ++j) {
            R[j] = sb1[j] + sW1[j*4+0]*v0 + sW1[j*4+1]*v1 + sW1[j*4+2]*v2 + sW1[j*4+3]*v3;
            S[j] = 0.0f;
            gwl[j] = gw[k*8 + j];
            gbl[j] = gb[k*8 + j];
        }
    }
    for (int e = 0; e < NEPOCH; ++e) {
        if (t < 8) Msum[t] = 0.0f;
        __syncthreads();
        float per[8];
        if (act) {
#pragma unroll
            for (int j = 0; j < 8; ++j) { per[j] = gwl[j]*S[j] + gbl[j]; atomicAdd(&Msum[j], per[j]); }
        }
        __syncthreads();
        if (act) {
            float M[8];
#pragma unroll
            for (int j = 0; j < 8; ++j) M[j] = Msum[j] - per[j];
            float gv[32];
#pragma unroll
            for (int gg = 0; gg < 32; ++gg) {
                float a = sb[gg];
#pragma unroll
                for (int j = 0; j < 8; ++j)
                    a = fmaf(R[j], sWih[gg*8+j], fmaf(M[j], sWhh[gg*8+j], a));
                gv[gg] = a;
            }
#pragma unroll
            for (int j = 0; j < 8; ++j) {
                float sg_i = frcp(1.f + ex2(-1.4426950408889634f * gv[j]));
                float sg_f = frcp(1.f + ex2(-1.4426950408889634f * gv[8+j]));
                float th_g = 1.f - 2.f * frcp(1.f + ex2(2.8853900817779268f * gv[16+j]));
                float sg_o = frcp(1.f + ex2(-1.4426950408889634f * gv[24+j]));
                float c2 = sg_f * S[j] + sg_i * th_g;
                float h2 = sg_o * (1.f - 2.f * frcp(1.f + ex2(2.8853900817779268f * c2)));
                R[j] += S[j];   // updateRelation uses OLD lastS
                S[j] = h2;
            }
        }
        __syncthreads();
    }
    if (act) {
        float* qp = q + ((size_t)f * KK + k) * 8;
#pragma unroll
        for (int jo = 0; jo < 8; ++jo) {
            float a = sb2[jo];
#pragma unroll
            for (int j = 0; j < 8; ++j) a = fmaf(fmaxf(R[j], 0.0f), sW2[jo*8+j], a);
            qp[jo] = a;
        }
    }
}

// ---------------- Phase 2: two skip-LSTM chains, DPP-exchange wavefront ----------------
// Block 0 = P chain (input q[u]), block 1 = V chain (input q[u]-q[u-67]).
// One wave per block; lane = l*8+s owns gate rows {i,f,g,o} x s of layer l.
// amdgpu_waves_per_eu(1,1): only 2 waves run on the whole GPU -> give the
// allocator the full VGPR budget so the 64-dword weight set stays resident
// (R4 spilled it to scratch: 4.4 GB FETCH_SIZE = 64 dwords/lane/step).
__global__ void
__attribute__((amdgpu_flat_work_group_size(64, 64), amdgpu_waves_per_eu(1, 1)))
slstm_kernel(
    const float* __restrict__ q,
    const float* __restrict__ pWih, const float* __restrict__ pWhh,
    const float* __restrict__ pbih, const float* __restrict__ pbhh,
    const float* __restrict__ vWih, const float* __restrict__ vWhh,
    const float* __restrict__ vbih, const float* __restrict__ vbhh,
    float* __restrict__ out, int U, int N)
{
    const int lane = threadIdx.x;
    const int l = lane >> 3, s = lane & 7;
    const int isV = blockIdx.x;
    const float* Wih = isV ? vWih : pWih;
    const float* Whh = isV ? vWhh : pWhh;
    const float* bi  = isV ? vbih : pbih;
    const float* bh  = isV ? vbhh : pbhh;
    float* ob = out + (size_t)isV * (size_t)N * 64;

    const float cS = -1.4426950408889634f;   // -log2(e): i,f,o rows (sigmoid)
    const float cT =  2.8853900817779268f;   // 2*log2(e): g row (tanh)

    // Gather slot k holds element j = s ^ M[k] (DPP butterfly order).
    const int M[8] = {0, 1, 2, 3, 7, 6, 5, 4};

    float2v wih01[8], wih23[8], whh01[8], whh23[8], b01, b23;
    {
        const int r_i = l*32 + 0*8 + s, r_f = l*32 + 1*8 + s;
        const int r_g = l*32 + 2*8 + s, r_o = l*32 + 3*8 + s;
#pragma unroll
        for (int k = 0; k < 8; ++k) {
            const int j = s ^ M[k];
            wih01[k] = float2v{cS * Wih[r_i*8+j], cS * Wih[r_f*8+j]};
            wih23[k] = float2v{cT * Wih[r_g*8+j], cS * Wih[r_o*8+j]};
            whh01[k] = float2v{cS * Whh[r_i*8+j], cS * Whh[r_f*8+j]};
            whh23[k] = float2v{cT * Whh[r_g*8+j], cS * Whh[r_o*8+j]};
        }
        b01 = float2v{cS*(bi[r_i]+bh[r_i]), cS*(bi[r_f]+bh[r_f])};
        b23 = float2v{cT*(bi[r_g]+bh[r_g]), cS*(bi[r_o]+bh[r_o])};
    }

    const int axo = ((lane + 56) & 63) << 2;   // pull y from lane-8 (group l-1)

    float hp = 0.f, c = 0.f, cs = 0.f, Hm = 0.f, Hc = 0.f;
    const bool g7 = (l == 7);
    const float vsel = isV ? 1.0f : 0.0f;

    float ysrcv = g7 ? q[s] : 0.f;   // seed: group 7 sources q(u=0)

    // core step. cs is the cT-pre-scaled cell state (saves a mul before the
    // tanh(c2) ex2 on the critical path); c is the true cell state (for Hc).
    auto core = [&](float& h2o, float& c2o, float& cso, float& xoo) {
        // h all-gather (pure VALU, ready early)
        const float hA = dppf<0xB1>(hp);
        const float hB = dppf<0x4E>(hp);
        const float hC = dppf<0x4E>(hA);
        const float hD = dppf<0x141>(hp);
        const float hE = dppf<0x141>(hA);
        const float hF = dppf<0x141>(hB);
        const float hG = dppf<0x141>(hC);
        const float2v hq0 = {hp, hA}, hq1 = {hB, hC}, hq2 = {hD, hE}, hq3 = {hF, hG};
        float2v g01 = {0.f, 0.f}, g23 = {0.f, 0.f};
        pkfma_lo(g01, hq0, whh01[0]); pkfma_hi(g01, hq0, whh01[1]);
        pkfma_lo(g23, hq0, whh23[0]); pkfma_hi(g23, hq0, whh23[1]);
        pkfma_lo(g01, hq1, whh01[2]); pkfma_hi(g01, hq1, whh01[3]);
        pkfma_lo(g23, hq1, whh23[2]); pkfma_hi(g23, hq1, whh23[3]);
        pkfma_lo(g01, hq2, whh01[4]); pkfma_hi(g01, hq2, whh01[5]);
        pkfma_lo(g23, hq2, whh23[4]); pkfma_hi(g23, hq2, whh23[5]);
        pkfma_lo(g01, hq3, whh01[6]); pkfma_hi(g01, hq3, whh01[7]);
        pkfma_lo(g23, hq3, whh23[6]); pkfma_hi(g23, hq3, whh23[7]);
        // x: one crossbar shift, then DPP all-gather
        const float ytmp = bperm(axo, ysrcv);
        const float xA = dppf<0xB1>(ytmp);
        const float xB = dppf<0x4E>(ytmp);
        const float xC = dppf<0x4E>(xA);
        const float xD = dppf<0x141>(ytmp);
        const float xE = dppf<0x141>(xA);
        const float xF = dppf<0x141>(xB);
        const float xG = dppf<0x141>(xC);
        const float2v xp0 = {ytmp, xA}, xp1 = {xB, xC}, xp2 = {xD, xE}, xp3 = {xF, xG};
        // two 4-deep chains per accumulator pair, then join
        float2v a01 = b01, a23 = b23;
        float2v u01 = {0.f, 0.f}, u23 = {0.f, 0.f};
        pkfma_lo(a01, xp0, wih01[0]); pkfma_hi(a01, xp0, wih01[1]);
        pkfma_lo(a23, xp0, wih23[0]); pkfma_hi(a23, xp0, wih23[1]);
        pkfma_lo(a01, xp1, wih01[2]); pkfma_hi(a01, xp1, wih01[3]);
        pkfma_lo(a23, xp1, wih23[2]); pkfma_hi(a23, xp1, wih23[3]);
        pkfma_lo(u01, xp2, wih01[4]); pkfma_hi(u01, xp2, wih01[5]);
        pkfma_lo(u23, xp2, wih23[4]); pkfma_hi(u23, xp2, wih23[5]);
        pkfma_lo(u01, xp3, wih01[6]); pkfma_hi(u01, xp3, wih01[7]);
        pkfma_lo(u23, xp3, wih23[6]); pkfma_hi(u23, xp3, wih23[7]);
        a01 = (a01 + u01) + g01;
        a23 = (a23 + u23) + g23;
        const float ig = frcp(1.f + ex2(a01.x));
        const float fg = frcp(1.f + ex2(a01.y));
        const float rg = frcp(1.f + ex2(a23.x));
        const float og = frcp(1.f + ex2(a23.y));
        const float gt  = fmaf(-2.f, rg, 1.f);            // tanh(g)
        const float gtT = fmaf(-2.f*cT, rg, cT);          // cT * tanh(g)
        const float c2  = fmaf(fg, c,  ig * gt);          // true cell
        const float cs2 = fmaf(fg, cs, ig * gtT);         // cT-scaled cell
        const float th = fmaf(-2.f, frcp(1.f + ex2(cs2)), 1.f);
        h2o = og * th;
        c2o = c2;
        cso = cs2;
        xoo = ytmp;
    };

    // ---- startup: d = 0..6 (direct loads, act = l <= d) ----
    for (int d = 0; d < 7; ++d) {
        float h2, c2n, csn, xo;
        core(h2, c2n, csn, xo);
        const bool act = (l <= d);
        hp = act ? h2 : 0.f;
        c  = act ? c2n : c;
        cs = act ? csn : cs;
        const float y = h2 + xo;
        const float qa = q[(d+1)*8 + s];   // u = d+1 <= 7 < 67: no V subtract
        ysrcv = g7 ? qa : y;
    }

    // ---- 8-deep prefetch ring (slot p consumes u = d0+1+p, refills u+8) ----
    float ra[8], rb[8];
#pragma unroll
    for (int p = 0; p < 8; ++p) { ra[p] = q[(8+p)*8 + s]; rb[p] = 0.f; }

    int d0 = 7;
    const int maxu = U - 1;
    for (int k = 0; k < N; ++k) {
        // 1064 clean steps: no boundary / activity logic at all
        for (int it = 0; it < 133; ++it) {
#pragma unroll
            for (int p = 0; p < 8; ++p) {
                const int u = d0 + 1 + p;
                float h2, c2n, csn, xo;
                core(h2, c2n, csn, xo);
                c = c2n;
                cs = csn;
                hp = h2;
                const float y = h2 + xo;
                const float qb = (u >= KK) ? rb[p] : 0.f;
                const float qc = fmaf(-vsel, qb, ra[p]);
                ysrcv = g7 ? qc : y;
                int ua = u + 8; if (ua > maxu) ua = maxu;
                ra[p] = q[ua*8 + s];
                int ub = ua - KK; if (ub < 0) ub = 0;
                rb[p] = q[ub*8 + s];
            }
            d0 += 8;
        }
        // boundary cluster: 8 steps, delta = 0..7; lane group l resets at delta == l
        const bool lastk = (k == N - 1);
#pragma unroll
        for (int p = 0; p < 8; ++p) {
            const int dlt = p;
            const int u = d0 + 1 + p;
            float h2, c2n, csn, xo;
            core(h2, c2n, csn, xo);
            const bool bnd = (l == dlt);
            const bool act = (!lastk) || (dlt <= l);
            const float HmN = Hm + h2, HcN = Hc + c2n;
            const float hpN = bnd ? HmN : h2;
            const float cN  = bnd ? HcN : c2n;
            const float csN = bnd ? cT * HcN : csn;
            hp = act ? hpN : hp;
            c  = act ? cN  : c;
            cs = act ? csN : cs;
            Hm = bnd ? HmN : Hm;
            Hc = bnd ? HcN : Hc;
            if (bnd) ob[(size_t)k * 64 + lane] = HmN;
            const float y = h2 + xo;
            const float qb = (u >= KK) ? rb[p] : 0.f;
            const float qc = fmaf(-vsel, qb, ra[p]);
            ysrcv = g7 ? qc : y;
            int ua = u + 8; if (ua > maxu) ua = maxu;
            ra[p] = q[ua*8 + s];
            int ub = ua - KK; if (ub < 0) ub = 0;
            rb[p] = q[ub*8 + s];
        }
        d0 += 8;
    }
}

extern "C" void kernel_launch(void* const* d_in, const int* in_sizes, int n_in,
                              void* d_out, int out_size, void* d_ws, size_t ws_size,
                              hipStream_t stream)
{
    const float* vid  = (const float*)d_in[0];
    const float* W1   = (const float*)d_in[1];
    const float* b1   = (const float*)d_in[2];
    const float* gw   = (const float*)d_in[3];
    const float* gb   = (const float*)d_in[4];
    const float* gWih = (const float*)d_in[5];
    const float* gWhh = (const float*)d_in[6];
    const float* gbih = (const float*)d_in[7];
    const float* gbhh = (const float*)d_in[8];
    const float* W2   = (const float*)d_in[9];
    const float* b2   = (const float*)d_in[10];
    const float* vWih = (const float*)d_in[11];
    const float* vWhh = (const float*)d_in[12];
    const float* vbih = (const float*)d_in[13];
    const float* vbhh = (const float*)d_in[14];
    const float* pWih = (const float*)d_in[15];
    const float* pWhh = (const float*)d_in[16];
    const float* pbih = (const float*)d_in[17];
    const float* pbhh = (const float*)d_in[18];

    const int T = in_sizes[0] / (KK * DIN);
    const int N = T / CLIPM;
    const int U = N * CLIPM * KK;
    float* q = (float*)d_ws;   // T*KK*8 floats = 4.4 MB

    grnn_kernel<<<dim3(T), dim3(128), 0, stream>>>(
        vid, W1, b1, gw, gb, gWih, gWhh, gbih, gbhh, W2, b2, q);
    slstm_kernel<<<dim3(2), dim3(64), 0, stream>>>(
        q, pWih, pWhh, pbih, pbhh, vWih, vWhh, vbih, vbhh, (float*)d_out, U, N);
}